// Round 1
// baseline (337.758 us; speedup 1.0000x reference)
//
#include <hip/hip_runtime.h>
#include <math.h>

// f32-rounded pi / 2pi, matching JAX's f64->f32 weak-type folding:
#define PI_F    3.14159274101257324e0f   /* 0x40490FDB */
#define TWOPI_F 6.28318548202514648e0f   /* 0x40C90FDB */
#define SENT_F  1000000.0f

// Compute duplicate mask for one group of N objects starting at object OFF.
// Bit (OFF+j) set  <=>  exists i>j in group with dR(i,j) < 0.05.
// Matches numpy f32 bit-exactly: fmod+adjust for jnp.mod, no FMA contraction,
// correctly-rounded sqrt.
template <int OFF, int N>
__device__ __forceinline__ unsigned group_dup(const float* __restrict__ r) {
    float e[N], p[N];
#pragma unroll
    for (int k = 0; k < N; ++k) {
        float pt = r[3 * (OFF + k) + 0];
        bool act = pt > 0.0f;
        e[k] = act ? r[3 * (OFF + k) + 1] : SENT_F;
        p[k] = act ? r[3 * (OFF + k) + 2] : SENT_F;
    }
    unsigned dup = 0;
#pragma unroll
    for (int j = 0; j < N - 1; ++j) {
        bool d = false;
#pragma unroll
        for (int i = j + 1; i < N; ++i) {
            float deta = e[i] - e[j];                      // plain sub: no contraction risk
            float dd   = (p[i] - p[j]) + PI_F;             // same assoc order as jnp
            float m    = fmodf(dd, TWOPI_F);               // exact remainder (lax.rem)
            m = (m < 0.0f) ? (m + TWOPI_F) : m;            // numpy-mod sign adjust
            float dphi = m - PI_F;
            // deta*deta + dphi*dphi WITHOUT fma contraction (match numpy rounding):
            float dr2 = __fadd_rn(__fmul_rn(deta, deta), __fmul_rn(dphi, dphi));
            float dr  = __fsqrt_rn(dr2);                   // correctly-rounded sqrt
            d = d || (dr < 0.05f);
        }
        if (d) dup |= (1u << (OFF + j));
    }
    return dup;
}

__global__ __launch_bounds__(256) void dup_removal_kernel(
    const float4* __restrict__ in, float4* __restrict__ out, int B) {
    int row = blockIdx.x * blockDim.x + threadIdx.x;
    if (row >= B) return;

    const float4* src = in + (size_t)row * 12;
    float4* dst = out + (size_t)row * 12;

    float r[48];
#pragma unroll
    for (int k = 0; k < 12; ++k) {
        float4 v = src[k];
        r[4 * k + 0] = v.x;
        r[4 * k + 1] = v.y;
        r[4 * k + 2] = v.z;
        r[4 * k + 3] = v.w;
    }

    unsigned dup = 0;
    dup |= group_dup<0, 6>(r);    // jets      (objects 0..5)
    dup |= group_dup<6, 3>(r);    // electrons (objects 6..8)
    dup |= group_dup<9, 3>(r);    // muons     (objects 9..11)
    dup |= group_dup<12, 3>(r);   // photons   (objects 12..14)
    // object 15 = MET: passthrough, never in dup mask.

#pragma unroll
    for (int o = 0; o < 15; ++o) {
        bool z = (dup >> o) & 1u;
        r[3 * o + 0] = z ? 0.0f : r[3 * o + 0];
        r[3 * o + 1] = z ? 0.0f : r[3 * o + 1];
        r[3 * o + 2] = z ? 0.0f : r[3 * o + 2];
    }

#pragma unroll
    for (int k = 0; k < 12; ++k) {
        float4 v;
        v.x = r[4 * k + 0];
        v.y = r[4 * k + 1];
        v.z = r[4 * k + 2];
        v.w = r[4 * k + 3];
        dst[k] = v;
    }
}

extern "C" void kernel_launch(void* const* d_in, const int* in_sizes, int n_in,
                              void* d_out, int out_size, void* d_ws, size_t ws_size,
                              hipStream_t stream) {
    const float4* x = (const float4*)d_in[0];
    float4* out = (float4*)d_out;
    int B = in_sizes[0] / 48;  // rows of (16,3)
    int block = 256;
    int grid = (B + block - 1) / block;
    dup_removal_kernel<<<grid, block, 0, stream>>>(x, out, B);
}